// Round 1
// baseline (436.720 us; speedup 1.0000x reference)
//
#include <hip/hip_runtime.h>
#include <hip/hip_bf16.h>
#include <math.h>

#define NTOK 16384
#define HDIM 1024
#define DSZ 32
#define DGZ 32
#define FMZ 64
#define NEXP 4
#define FFZ 2048

typedef __attribute__((ext_vector_type(4))) float f32x4;
typedef __attribute__((ext_vector_type(8))) short bf16x8;

__device__ __forceinline__ unsigned short f2bf(float f){
    union { float f; unsigned int u; } v; v.f = f;
    unsigned int r = (v.u + 0x7FFFu + ((v.u >> 16) & 1u)) >> 16;
    return (unsigned short)r;
}
__device__ __forceinline__ float gelu_f(float x){
    return 0.5f * x * (1.0f + erff(x * 0.70710678118654752440f));
}
__device__ __forceinline__ void gld_lds16(const void* g, void* s){
    __builtin_amdgcn_global_load_lds((const __attribute__((address_space(1))) unsigned int*)g,
                                     (__attribute__((address_space(3))) unsigned int*)s, 16, 0, 0);
}

// ---------------- kernel 1: per-token LN stats + h -> bf16 ----------------
__global__ __launch_bounds__(256) void k_stats(const float* __restrict__ h,
        unsigned short* __restrict__ hbf, float* __restrict__ mu_g, float* __restrict__ rs_g){
    int tid = threadIdx.x;
    int wv = tid >> 6, l = tid & 63;
    int tok = blockIdx.x * 4 + wv;
    const float4* hp = (const float4*)(h + (size_t)tok * HDIM);
    ushort4* op = (ushort4*)(hbf + (size_t)tok * HDIM);
    float s = 0.f, s2 = 0.f;
    #pragma unroll
    for (int p = 0; p < 4; ++p){
        float4 v = hp[p * 64 + l];
        s  += v.x + v.y + v.z + v.w;
        s2 += v.x*v.x + v.y*v.y + v.z*v.z + v.w*v.w;
        ushort4 o; o.x = f2bf(v.x); o.y = f2bf(v.y); o.z = f2bf(v.z); o.w = f2bf(v.w);
        op[p * 64 + l] = o;
    }
    #pragma unroll
    for (int off = 32; off >= 1; off >>= 1){
        s  += __shfl_xor(s,  off, 64);
        s2 += __shfl_xor(s2, off, 64);
    }
    if (l == 0){
        float mu = s * (1.0f / HDIM);
        float var = s2 * (1.0f / HDIM) - mu * mu;
        var = fmaxf(var, 0.f);
        mu_g[tok] = mu;
        rs_g[tok] = 1.0f / sqrtf(var + 1e-5f);
    }
}

// ---------------- kernel 2: transpose + fp32->bf16 (weights, per expert) ----------------
// out[c][r] = in[r][c];  grid (C/32, R/32, E), block (32, 8)
__global__ __launch_bounds__(256) void k_transpose_bf(const float* __restrict__ in,
        unsigned short* __restrict__ out, int R, int C){
    __shared__ float tile[32][33];
    size_t mat = (size_t)blockIdx.z * R * C;
    int bx = blockIdx.x * 32;   // col base
    int by = blockIdx.y * 32;   // row base
    int x = threadIdx.x, y = threadIdx.y;
    const float* ip = in + mat;
    unsigned short* op = out + mat;
    #pragma unroll
    for (int i = 0; i < 32; i += 8)
        tile[y + i][x] = ip[(size_t)(by + y + i) * C + (bx + x)];
    __syncthreads();
    #pragma unroll
    for (int i = 0; i < 32; i += 8)
        op[(size_t)(bx + y + i) * R + (by + x)] = f2bf(tile[x][y + i]);
}

// ---------------- kernel 3: fused fp32 routing ----------------
// 64 tokens per block, 256 threads, grid 256.
__global__ __launch_bounds__(256) void k_route(
    const float* __restrict__ h, const float* __restrict__ tok_emb,
    const float* __restrict__ ln_g, const float* __restrict__ ln_b,
    const float* __restrict__ Wg, const float* __restrict__ bg,
    const float* __restrict__ Wf, const float* __restrict__ bfv,
    const float* __restrict__ Wr, const float* __restrict__ br,
    const float* __restrict__ mu_g, const float* __restrict__ rs_g,
    float* __restrict__ tprob, int* __restrict__ list, int* __restrict__ cnt,
    float* __restrict__ imp_part)
{
    __shared__ __align__(16) char smem[62208];
    float* lgs  = (float*)(smem);                      // [1024]
    float* lbs  = (float*)(smem + 4096);               // [1024]
    float (*hsT)[64]  = (float(*)[64])(smem + 8192);   // [64 k][64 tok]
    float (*wgs)[32]  = (float(*)[32])(smem + 24576);  // [64 k][32 c]
    float (*gacc)[32] = (float(*)[32])(smem + 32768);  // [64 tok][32 c]
    float* mus = (float*)(smem + 40960);               // [64]
    float* rss = (float*)(smem + 41216);               // [64]
    float (*wrs)[4]     = (float(*)[4])(smem + 41472); // [64][4]
    float (*logit_s)[5] = (float(*)[5])(smem + 42496);
    float (*prob_s)[5]  = (float(*)[5])(smem + 43776);
    int* lcnt  = (int*)(smem + 45056);
    int* lbase = (int*)(smem + 45072);
    // phase-U overlays (hsT/wgs/lgs/lbs dead by then):
    float (*agT)[64] = (float(*)[64])(smem);           // [64 j][64 tok]
    float (*wfs)[64] = (float(*)[64])(smem + 16384);   // [64 k][64 f]
    float (*uT)[64]  = (float(*)[64])(smem + 45824);   // [64 f][64 tok]

    int tid = threadIdx.x;
    int t0 = blockIdx.x * 64;

    ((float4*)lgs)[tid] = ((const float4*)ln_g)[tid];
    ((float4*)lbs)[tid] = ((const float4*)ln_b)[tid];
    if (tid < 64){ mus[tid] = mu_g[t0 + tid]; rss[tid] = rs_g[t0 + tid]; }
    if (tid < 64) ((float4*)wrs)[tid] = ((const float4*)Wr)[tid];
    if (tid < 4) lcnt[tid] = 0;
    __syncthreads();

    // ---- phase G: gacc[t][c] = (LN(h) @ Wg)[t][c], fp32 ----
    int l = tid & 63, w = tid >> 6;
    int tg = l & 7, cg = l >> 3, q = w;   // token-group(8), col-group(4), k-quarter
    float g_[8][4];
    #pragma unroll
    for (int i=0;i<8;++i){ g_[i][0]=0.f; g_[i][1]=0.f; g_[i][2]=0.f; g_[i][3]=0.f; }
    int tokrow = tid >> 2;
    float m_ = mus[tokrow], r_ = rss[tokrow];
    const float* hrow = h + (size_t)(t0 + tokrow) * HDIM;

    for (int k0 = 0; k0 < HDIM; k0 += 64){
        // stage transformed h_ln transposed: hsT[k][tok]
        #pragma unroll
        for (int p = 0; p < 4; ++p){
            int f4 = (tid & 3) + 4 * p;                 // 0..15
            float4 v = ((const float4*)(hrow + k0))[f4];
            int c = f4 * 4;
            hsT[c+0][tokrow] = (v.x - m_) * r_ * lgs[k0+c+0] + lbs[k0+c+0];
            hsT[c+1][tokrow] = (v.y - m_) * r_ * lgs[k0+c+1] + lbs[k0+c+1];
            hsT[c+2][tokrow] = (v.z - m_) * r_ * lgs[k0+c+2] + lbs[k0+c+2];
            hsT[c+3][tokrow] = (v.w - m_) * r_ * lgs[k0+c+3] + lbs[k0+c+3];
        }
        {   // stage Wg tile [64][32]
            int wgrow = tid >> 2;
            #pragma unroll
            for (int p = 0; p < 2; ++p){
                int f4 = (tid & 3) + 4 * p;             // 0..7
                ((float4*)wgs[wgrow])[f4] = ((const float4*)(Wg + (size_t)(k0 + wgrow) * DGZ))[f4];
            }
        }
        __syncthreads();
        #pragma unroll
        for (int kk16 = 0; kk16 < 16; ++kk16){
            int kk = q * 16 + kk16;
            float4 a0 = ((float4*)hsT[kk])[tg*2];
            float4 a1 = ((float4*)hsT[kk])[tg*2+1];
            float4 wv = ((float4*)wgs[kk])[cg];
            float av[8] = {a0.x,a0.y,a0.z,a0.w,a1.x,a1.y,a1.z,a1.w};
            float wj[4] = {wv.x,wv.y,wv.z,wv.w};
            #pragma unroll
            for (int i=0;i<8;++i){
                g_[i][0] += av[i]*wj[0]; g_[i][1] += av[i]*wj[1];
                g_[i][2] += av[i]*wj[2]; g_[i][3] += av[i]*wj[3];
            }
        }
        __syncthreads();
    }
    // reduce k-quarter partials into gacc (sequential by wave; deterministic)
    for (int qq = 0; qq < 4; ++qq){
        if (w == qq){
            #pragma unroll
            for (int i=0;i<8;++i){
                int tok = tg*8+i;
                #pragma unroll
                for (int j=0;j<4;++j){
                    int c = cg*4+j;
                    if (qq == 0) gacc[tok][c] = g_[i][j];
                    else gacc[tok][c] += g_[i][j];
                }
            }
        }
        __syncthreads();
    }
    // ---- build agT = [tok_emb ; gelu(gacc+bg)]^T and stage Wf ----
    {
        int tokr = tid >> 2;
        #pragma unroll
        for (int p = 0; p < 2; ++p){
            int f4 = (tid & 3) + 4*p;                   // 0..7
            float4 v = ((const float4*)(tok_emb + (size_t)(t0 + tokr) * DSZ))[f4];
            int j = f4 * 4;
            agT[j+0][tokr] = v.x; agT[j+1][tokr] = v.y;
            agT[j+2][tokr] = v.z; agT[j+3][tokr] = v.w;
        }
        int c = tid & 31, tok8 = (tid >> 5) * 8;
        float bgc = bg[c];
        #pragma unroll
        for (int i=0;i<8;++i){
            int tok = tok8 + i;
            agT[32 + c][tok] = gelu_f(gacc[tok][c] + bgc);
        }
        int row = tid >> 2;
        #pragma unroll
        for (int p = 0; p < 4; ++p){
            int f4 = (tid & 3) + 4*p;                   // 0..15
            ((float4*)wfs[row])[f4] = ((const float4*)(Wf + (size_t)row * FMZ))[f4];
        }
    }
    __syncthreads();
    // ---- phase U: uT[f][tok] = gelu(sum_j agT[j][tok]*Wf[j][f] + bf[f]) ----
    {
        int tok = tid & 63, fq = tid >> 6;
        float u_[16];
        #pragma unroll
        for (int i=0;i<16;++i) u_[i]=0.f;
        for (int j = 0; j < 64; ++j){
            float a = agT[j][tok];
            float wv[16];
            *(float4*)&wv[0]  = ((float4*)wfs[j])[fq*4+0];
            *(float4*)&wv[4]  = ((float4*)wfs[j])[fq*4+1];
            *(float4*)&wv[8]  = ((float4*)wfs[j])[fq*4+2];
            *(float4*)&wv[12] = ((float4*)wfs[j])[fq*4+3];
            #pragma unroll
            for (int i=0;i<16;++i) u_[i] += a * wv[i];
        }
        #pragma unroll
        for (int i=0;i<16;++i){
            int f = fq*16+i;
            uT[f][tok] = gelu_f(u_[i] + bfv[f]);
        }
    }
    __syncthreads();
    // ---- logits ----
    {
        int tok = tid & 63, e = tid >> 6;
        float lt = 0.f;
        #pragma unroll 8
        for (int f = 0; f < 64; ++f) lt += uT[f][tok] * wrs[f][e];
        logit_s[tok][e] = lt + br[e];
    }
    __syncthreads();
    // ---- softmax / top-1 / scatter ----
    int my_e = 0, my_pos = 0;
    if (tid < 64){
        int tok = tid;
        float l0 = logit_s[tok][0], l1 = logit_s[tok][1];
        float l2 = logit_s[tok][2], l3 = logit_s[tok][3];
        float mx = fmaxf(fmaxf(l0,l1), fmaxf(l2,l3));
        float p0 = expf(l0-mx), p1 = expf(l1-mx), p2 = expf(l2-mx), p3 = expf(l3-mx);
        float inv = 1.0f / (p0+p1+p2+p3);
        int be = 0; float bp = p0;
        if (p1 > bp){ bp = p1; be = 1; }
        if (p2 > bp){ bp = p2; be = 2; }
        if (p3 > bp){ bp = p3; be = 3; }
        tprob[t0 + tok] = bp * inv;
        prob_s[tok][0] = p0*inv; prob_s[tok][1] = p1*inv;
        prob_s[tok][2] = p2*inv; prob_s[tok][3] = p3*inv;
        my_e = be;
        my_pos = atomicAdd(&lcnt[be], 1);
    }
    __syncthreads();
    if (tid < 4) lbase[tid] = atomicAdd(&cnt[tid], lcnt[tid]);
    __syncthreads();
    if (tid < 64) list[my_e * NTOK + lbase[my_e] + my_pos] = t0 + tid;
    if (tid < 4){
        float s = 0.f;
        for (int t = 0; t < 64; ++t) s += prob_s[t][tid];
        imp_part[blockIdx.x * 4 + tid] = s;
    }
}

// ---------------- grouped expert GEMM (m97-style 128x128 tile, bf16 MFMA) ----------------
// A rows gathered by token id from list[e]; B is N-major bf16 [E][NT][KT].
// PH1: C = gelu(A@B + bias) -> A1[tok][FFZ] bf16
// !PH1: out[tok][col] = h[tok][col] + 0.5*tprob[tok]*(A@B + bias)
template<int KT, int NT, bool PH1>
__global__ __launch_bounds__(256) void k_gemm(
    const unsigned short* __restrict__ Abase,
    const unsigned short* __restrict__ Bbase,
    const int* __restrict__ list, const int* __restrict__ cnt_g,
    const float* __restrict__ bias,
    unsigned short* __restrict__ A1out,
    const float* __restrict__ hres,
    const float* __restrict__ tprob,
    float* __restrict__ outp)
{
    int e = blockIdx.z;
    int cnt = cnt_g[e];
    int m0 = blockIdx.y * 128;
    if (m0 >= cnt) return;
    int n0 = blockIdx.x * 128;
    int tid = threadIdx.x, w = tid >> 6, l = tid & 63;
    int wr = w >> 1, wc = w & 1;
    __shared__ __align__(16) unsigned short As[128*64];
    __shared__ __align__(16) unsigned short Bs[128*64];

    const unsigned short* aptr[4];
    const unsigned short* bptr[4];
    #pragma unroll
    for (int i = 0; i < 4; ++i){
        int row = 8*w + (l>>3) + 32*i;
        int g = m0 + row; if (g > cnt-1) g = cnt-1;
        int tok = list[e * NTOK + g];
        aptr[i] = Abase + (size_t)tok * KT + (l&7)*8;
        bptr[i] = Bbase + ((size_t)e * NT + (n0 + row)) * KT + (l&7)*8;
    }
    f32x4 acc[4][4] = {};
    for (int k0 = 0; k0 < KT; k0 += 64){
        #pragma unroll
        for (int i = 0; i < 4; ++i)
            gld_lds16(aptr[i] + k0, (char*)As + w*1024 + i*4096);
        #pragma unroll
        for (int i = 0; i < 4; ++i)
            gld_lds16(bptr[i] + k0, (char*)Bs + w*1024 + i*4096);
        __syncthreads();
        #pragma unroll
        for (int kk = 0; kk < 2; ++kk){
            bf16x8 a[4], b[4];
            #pragma unroll
            for (int m = 0; m < 4; ++m)
                a[m] = *(const bf16x8*)((const char*)As + (wr*64 + m*16 + (l&15))*128 + kk*64 + (l>>4)*16);
            #pragma unroll
            for (int n = 0; n < 4; ++n)
                b[n] = *(const bf16x8*)((const char*)Bs + (wc*64 + n*16 + (l&15))*128 + kk*64 + (l>>4)*16);
            #pragma unroll
            for (int m = 0; m < 4; ++m)
                #pragma unroll
                for (int n = 0; n < 4; ++n)
                    acc[m][n] = __builtin_amdgcn_mfma_f32_16x16x32_bf16(a[m], b[n], acc[m][n], 0, 0, 0);
        }
        __syncthreads();
    }
    // epilogue: C/D layout col = lane&15, row = (lane>>4)*4 + reg
    #pragma unroll
    for (int m = 0; m < 4; ++m){
        #pragma unroll
        for (int r = 0; r < 4; ++r){
            int row = wr*64 + m*16 + (l>>4)*4 + r;
            int g = m0 + row;
            if (g < cnt){
                int tok = list[e*NTOK + g];
                if (PH1){
                    #pragma unroll
                    for (int n = 0; n < 4; ++n){
                        int col = n0 + wc*64 + n*16 + (l&15);
                        float v = acc[m][n][r] + bias[e*NT + col];
                        A1out[(size_t)tok * FFZ + col] = f2bf(gelu_f(v));
                    }
                } else {
                    float sc = 0.5f * tprob[tok];
                    #pragma unroll
                    for (int n = 0; n < 4; ++n){
                        int col = n0 + wc*64 + n*16 + (l&15);
                        float v = acc[m][n][r] + bias[e*NT + col];
                        size_t o = (size_t)tok * HDIM + col;
                        outp[o] = hres[o] + sc * v;
                    }
                }
            }
        }
    }
}

// ---------------- final: lb_loss ----------------
__global__ void k_final(const float* __restrict__ imp_part, const int* __restrict__ cnt,
                        float* __restrict__ outp){
    __shared__ float imp_s[4];
    int tid = threadIdx.x;
    if (tid < 4){
        float s = 0.f;
        for (int b = 0; b < 256; ++b) s += imp_part[b*4 + tid];
        imp_s[tid] = s;
    }
    __syncthreads();
    if (tid == 0){
        float lb = 0.f;
        #pragma unroll
        for (int e = 0; e < 4; ++e) lb += imp_s[e] * (float)cnt[e];
        outp[(size_t)NTOK * HDIM] = (float)NEXP * lb / ((float)NTOK * (float)NTOK + 1e-8f);
    }
}

extern "C" void kernel_launch(void* const* d_in, const int* in_sizes, int n_in,
                              void* d_out, int out_size, void* d_ws, size_t ws_size,
                              hipStream_t stream){
    const float* h       = (const float*)d_in[0];
    const float* tok_emb = (const float*)d_in[1];
    // d_in[2] = is_mask (unused by the reference math)
    const float* ln_g = (const float*)d_in[3];
    const float* ln_b = (const float*)d_in[4];
    const float* Wg   = (const float*)d_in[5];
    const float* bg   = (const float*)d_in[6];
    const float* Wf   = (const float*)d_in[7];
    const float* bfv  = (const float*)d_in[8];
    const float* Wr   = (const float*)d_in[9];
    const float* br   = (const float*)d_in[10];
    const float* W1   = (const float*)d_in[11];
    const float* b1   = (const float*)d_in[12];
    const float* W2   = (const float*)d_in[13];
    const float* b2   = (const float*)d_in[14];
    float* outp = (float*)d_out;
    char* ws = (char*)d_ws;

    // workspace layout (needs ~134.7 MB)
    unsigned short* h_bf = (unsigned short*)(ws);               // 33554432 B
    unsigned short* W1T  = (unsigned short*)(ws + 33554432);    // 16777216 B  [E][FFZ][HDIM]
    unsigned short* W2T  = (unsigned short*)(ws + 50331648);    // 16777216 B  [E][HDIM][FFZ]
    unsigned short* A1   = (unsigned short*)(ws + 67108864);    // 67108864 B  [NTOK][FFZ]
    float* mu_g  = (float*)(ws + 134217728);
    float* rs_g  = (float*)(ws + 134283264);
    float* tprob = (float*)(ws + 134348800);
    int*   list  = (int*)(ws + 134414336);                      // [E][NTOK]
    int*   cnt   = (int*)(ws + 134676480);                      // [E]
    float* imp   = (float*)(ws + 134676736);                    // [256][E]

    hipMemsetAsync(cnt, 0, NEXP * sizeof(int), stream);
    k_stats<<<NTOK/4, 256, 0, stream>>>(h, h_bf, mu_g, rs_g);
    k_transpose_bf<<<dim3(FFZ/32, HDIM/32, NEXP), dim3(32,8), 0, stream>>>(W1, W1T, HDIM, FFZ);
    k_transpose_bf<<<dim3(HDIM/32, FFZ/32, NEXP), dim3(32,8), 0, stream>>>(W2, W2T, FFZ, HDIM);
    k_route<<<NTOK/64, 256, 0, stream>>>(h, tok_emb, ln_g, ln_b, Wg, bg, Wf, bfv, Wr, br,
                                         mu_g, rs_g, tprob, list, cnt, imp);
    k_gemm<HDIM, FFZ, true><<<dim3(FFZ/128, NTOK/128, NEXP), 256, 0, stream>>>(
        h_bf, W1T, list, cnt, b1, A1, nullptr, nullptr, nullptr);
    k_gemm<FFZ, HDIM, false><<<dim3(HDIM/128, NTOK/128, NEXP), 256, 0, stream>>>(
        A1, W2T, list, cnt, b2, nullptr, h, tprob, outp);
    k_final<<<1, 64, 0, stream>>>(imp, cnt, outp);
}

// Round 2
// 393.618 us; speedup vs baseline: 1.1095x; 1.1095x over previous
//
#include <hip/hip_runtime.h>
#include <hip/hip_bf16.h>
#include <math.h>

#define NTOK 16384
#define HDIM 1024
#define DSZ 32
#define DGZ 32
#define FMZ 64
#define NEXP 4
#define FFZ 2048

typedef __attribute__((ext_vector_type(4))) float f32x4;
typedef __attribute__((ext_vector_type(8))) short bf16x8;

__device__ __forceinline__ unsigned short f2bf(float f){
    union { float f; unsigned int u; } v; v.f = f;
    unsigned int r = (v.u + 0x7FFFu + ((v.u >> 16) & 1u)) >> 16;
    return (unsigned short)r;
}
__device__ __forceinline__ float gelu_f(float x){
    return 0.5f * x * (1.0f + erff(x * 0.70710678118654752440f));
}
__device__ __forceinline__ void gld_lds16(const void* g, void* s){
    __builtin_amdgcn_global_load_lds((const __attribute__((address_space(1))) unsigned int*)g,
                                     (__attribute__((address_space(3))) unsigned int*)s, 16, 0, 0);
}

// ---------------- kernel 1: per-token LN stats + h -> bf16 ----------------
__global__ __launch_bounds__(256) void k_stats(const float* __restrict__ h,
        unsigned short* __restrict__ hbf, float* __restrict__ mu_g, float* __restrict__ rs_g){
    int tid = threadIdx.x;
    int wv = tid >> 6, l = tid & 63;
    int tok = blockIdx.x * 4 + wv;
    const float4* hp = (const float4*)(h + (size_t)tok * HDIM);
    ushort4* op = (ushort4*)(hbf + (size_t)tok * HDIM);
    float s = 0.f, s2 = 0.f;
    #pragma unroll
    for (int p = 0; p < 4; ++p){
        float4 v = hp[p * 64 + l];
        s  += v.x + v.y + v.z + v.w;
        s2 += v.x*v.x + v.y*v.y + v.z*v.z + v.w*v.w;
        ushort4 o; o.x = f2bf(v.x); o.y = f2bf(v.y); o.z = f2bf(v.z); o.w = f2bf(v.w);
        op[p * 64 + l] = o;
    }
    #pragma unroll
    for (int off = 32; off >= 1; off >>= 1){
        s  += __shfl_xor(s,  off, 64);
        s2 += __shfl_xor(s2, off, 64);
    }
    if (l == 0){
        float mu = s * (1.0f / HDIM);
        float var = s2 * (1.0f / HDIM) - mu * mu;
        var = fmaxf(var, 0.f);
        mu_g[tok] = mu;
        rs_g[tok] = 1.0f / sqrtf(var + 1e-5f);
    }
}

// ---------------- kernel 2: transpose + fp32->bf16 (weights, per expert) ----------------
// out[c][r] = in[r][c];  grid (C/32, R/32, E), block (32, 8)
__global__ __launch_bounds__(256) void k_transpose_bf(const float* __restrict__ in,
        unsigned short* __restrict__ out, int R, int C){
    __shared__ float tile[32][33];
    size_t mat = (size_t)blockIdx.z * R * C;
    int bx = blockIdx.x * 32;   // col base
    int by = blockIdx.y * 32;   // row base
    int x = threadIdx.x, y = threadIdx.y;
    const float* ip = in + mat;
    unsigned short* op = out + mat;
    #pragma unroll
    for (int i = 0; i < 32; i += 8)
        tile[y + i][x] = ip[(size_t)(by + y + i) * C + (bx + x)];
    __syncthreads();
    #pragma unroll
    for (int i = 0; i < 32; i += 8)
        op[(size_t)(bx + y + i) * R + (by + x)] = f2bf(tile[x][y + i]);
}

// ---------------- kernel 3: fused fp32 routing ----------------
// 64 tokens per block, 256 threads, grid 256.
__global__ __launch_bounds__(256) void k_route(
    const float* __restrict__ h, const float* __restrict__ tok_emb,
    const float* __restrict__ ln_g, const float* __restrict__ ln_b,
    const float* __restrict__ Wg, const float* __restrict__ bg,
    const float* __restrict__ Wf, const float* __restrict__ bfv,
    const float* __restrict__ Wr, const float* __restrict__ br,
    const float* __restrict__ mu_g, const float* __restrict__ rs_g,
    float* __restrict__ tprob, int* __restrict__ list, int* __restrict__ cnt,
    float* __restrict__ imp_part)
{
    __shared__ __align__(16) char smem[62208];
    float* lgs  = (float*)(smem);                      // [1024]
    float* lbs  = (float*)(smem + 4096);               // [1024]
    float (*hsT)[64]  = (float(*)[64])(smem + 8192);   // [64 k][64 tok]
    float (*wgs)[32]  = (float(*)[32])(smem + 24576);  // [64 k][32 c]
    float (*gacc)[32] = (float(*)[32])(smem + 32768);  // [64 tok][32 c]
    float* mus = (float*)(smem + 40960);               // [64]
    float* rss = (float*)(smem + 41216);               // [64]
    float (*wrs)[4]     = (float(*)[4])(smem + 41472); // [64][4]
    float (*logit_s)[5] = (float(*)[5])(smem + 42496);
    float (*prob_s)[5]  = (float(*)[5])(smem + 43776);
    int* lcnt  = (int*)(smem + 45056);
    int* lbase = (int*)(smem + 45072);
    // phase-U overlays (hsT/wgs/lgs/lbs dead by then):
    float (*agT)[64] = (float(*)[64])(smem);           // [64 j][64 tok]
    float (*wfs)[64] = (float(*)[64])(smem + 16384);   // [64 k][64 f]
    float (*uT)[64]  = (float(*)[64])(smem + 45824);   // [64 f][64 tok]

    int tid = threadIdx.x;
    int t0 = blockIdx.x * 64;

    ((float4*)lgs)[tid] = ((const float4*)ln_g)[tid];
    ((float4*)lbs)[tid] = ((const float4*)ln_b)[tid];
    if (tid < 64){ mus[tid] = mu_g[t0 + tid]; rss[tid] = rs_g[t0 + tid]; }
    if (tid < 64) ((float4*)wrs)[tid] = ((const float4*)Wr)[tid];
    if (tid < 4) lcnt[tid] = 0;
    __syncthreads();

    // ---- phase G: gacc[t][c] = (LN(h) @ Wg)[t][c], fp32 ----
    int l = tid & 63, w = tid >> 6;
    int tg = l & 7, cg = l >> 3, q = w;   // token-group(8), col-group(4), k-quarter
    float g_[8][4];
    #pragma unroll
    for (int i=0;i<8;++i){ g_[i][0]=0.f; g_[i][1]=0.f; g_[i][2]=0.f; g_[i][3]=0.f; }
    int tokrow = tid >> 2;
    float m_ = mus[tokrow], r_ = rss[tokrow];
    const float* hrow = h + (size_t)(t0 + tokrow) * HDIM;

    for (int k0 = 0; k0 < HDIM; k0 += 64){
        // stage transformed h_ln transposed: hsT[k][tok]
        #pragma unroll
        for (int p = 0; p < 4; ++p){
            int f4 = (tid & 3) + 4 * p;                 // 0..15
            float4 v = ((const float4*)(hrow + k0))[f4];
            int c = f4 * 4;
            hsT[c+0][tokrow] = (v.x - m_) * r_ * lgs[k0+c+0] + lbs[k0+c+0];
            hsT[c+1][tokrow] = (v.y - m_) * r_ * lgs[k0+c+1] + lbs[k0+c+1];
            hsT[c+2][tokrow] = (v.z - m_) * r_ * lgs[k0+c+2] + lbs[k0+c+2];
            hsT[c+3][tokrow] = (v.w - m_) * r_ * lgs[k0+c+3] + lbs[k0+c+3];
        }
        {   // stage Wg tile [64][32]
            int wgrow = tid >> 2;
            #pragma unroll
            for (int p = 0; p < 2; ++p){
                int f4 = (tid & 3) + 4 * p;             // 0..7
                ((float4*)wgs[wgrow])[f4] = ((const float4*)(Wg + (size_t)(k0 + wgrow) * DGZ))[f4];
            }
        }
        __syncthreads();
        #pragma unroll
        for (int kk16 = 0; kk16 < 16; ++kk16){
            int kk = q * 16 + kk16;
            float4 a0 = ((float4*)hsT[kk])[tg*2];
            float4 a1 = ((float4*)hsT[kk])[tg*2+1];
            float4 wv = ((float4*)wgs[kk])[cg];
            float av[8] = {a0.x,a0.y,a0.z,a0.w,a1.x,a1.y,a1.z,a1.w};
            float wj[4] = {wv.x,wv.y,wv.z,wv.w};
            #pragma unroll
            for (int i=0;i<8;++i){
                g_[i][0] += av[i]*wj[0]; g_[i][1] += av[i]*wj[1];
                g_[i][2] += av[i]*wj[2]; g_[i][3] += av[i]*wj[3];
            }
        }
        __syncthreads();
    }
    // reduce k-quarter partials into gacc (sequential by wave; deterministic)
    for (int qq = 0; qq < 4; ++qq){
        if (w == qq){
            #pragma unroll
            for (int i=0;i<8;++i){
                int tok = tg*8+i;
                #pragma unroll
                for (int j=0;j<4;++j){
                    int c = cg*4+j;
                    if (qq == 0) gacc[tok][c] = g_[i][j];
                    else gacc[tok][c] += g_[i][j];
                }
            }
        }
        __syncthreads();
    }
    // ---- build agT = [tok_emb ; gelu(gacc+bg)]^T and stage Wf ----
    {
        int tokr = tid >> 2;
        #pragma unroll
        for (int p = 0; p < 2; ++p){
            int f4 = (tid & 3) + 4*p;                   // 0..7
            float4 v = ((const float4*)(tok_emb + (size_t)(t0 + tokr) * DSZ))[f4];
            int j = f4 * 4;
            agT[j+0][tokr] = v.x; agT[j+1][tokr] = v.y;
            agT[j+2][tokr] = v.z; agT[j+3][tokr] = v.w;
        }
        int c = tid & 31, tok8 = (tid >> 5) * 8;
        float bgc = bg[c];
        #pragma unroll
        for (int i=0;i<8;++i){
            int tok = tok8 + i;
            agT[32 + c][tok] = gelu_f(gacc[tok][c] + bgc);
        }
        int row = tid >> 2;
        #pragma unroll
        for (int p = 0; p < 4; ++p){
            int f4 = (tid & 3) + 4*p;                   // 0..15
            ((float4*)wfs[row])[f4] = ((const float4*)(Wf + (size_t)row * FMZ))[f4];
        }
    }
    __syncthreads();
    // ---- phase U: uT[f][tok] = gelu(sum_j agT[j][tok]*Wf[j][f] + bf[f]) ----
    {
        int tok = tid & 63, fq = tid >> 6;
        float u_[16];
        #pragma unroll
        for (int i=0;i<16;++i) u_[i]=0.f;
        for (int j = 0; j < 64; ++j){
            float a = agT[j][tok];
            float wv[16];
            *(float4*)&wv[0]  = ((float4*)wfs[j])[fq*4+0];
            *(float4*)&wv[4]  = ((float4*)wfs[j])[fq*4+1];
            *(float4*)&wv[8]  = ((float4*)wfs[j])[fq*4+2];
            *(float4*)&wv[12] = ((float4*)wfs[j])[fq*4+3];
            #pragma unroll
            for (int i=0;i<16;++i) u_[i] += a * wv[i];
        }
        #pragma unroll
        for (int i=0;i<16;++i){
            int f = fq*16+i;
            uT[f][tok] = gelu_f(u_[i] + bfv[f]);
        }
    }
    __syncthreads();
    // ---- logits ----
    {
        int tok = tid & 63, e = tid >> 6;
        float lt = 0.f;
        #pragma unroll 8
        for (int f = 0; f < 64; ++f) lt += uT[f][tok] * wrs[f][e];
        logit_s[tok][e] = lt + br[e];
    }
    __syncthreads();
    // ---- softmax / top-1 / scatter ----
    int my_e = 0, my_pos = 0;
    if (tid < 64){
        int tok = tid;
        float l0 = logit_s[tok][0], l1 = logit_s[tok][1];
        float l2 = logit_s[tok][2], l3 = logit_s[tok][3];
        float mx = fmaxf(fmaxf(l0,l1), fmaxf(l2,l3));
        float p0 = expf(l0-mx), p1 = expf(l1-mx), p2 = expf(l2-mx), p3 = expf(l3-mx);
        float inv = 1.0f / (p0+p1+p2+p3);
        int be = 0; float bp = p0;
        if (p1 > bp){ bp = p1; be = 1; }
        if (p2 > bp){ bp = p2; be = 2; }
        if (p3 > bp){ bp = p3; be = 3; }
        tprob[t0 + tok] = bp * inv;
        prob_s[tok][0] = p0*inv; prob_s[tok][1] = p1*inv;
        prob_s[tok][2] = p2*inv; prob_s[tok][3] = p3*inv;
        my_e = be;
        my_pos = atomicAdd(&lcnt[be], 1);
    }
    __syncthreads();
    if (tid < 4) lbase[tid] = atomicAdd(&cnt[tid], lcnt[tid]);
    __syncthreads();
    if (tid < 64) list[my_e * NTOK + lbase[my_e] + my_pos] = t0 + tid;
    if (tid < 4){
        float s = 0.f;
        for (int t = 0; t < 64; ++t) s += prob_s[t][tid];
        imp_part[blockIdx.x * 4 + tid] = s;
    }
}

// ---------------- grouped expert GEMM (m97-style 128x128 tile, bf16 MFMA) ----------------
// A rows gathered by token id from list[e]; B is N-major bf16 [E][NT][KT].
// LDS tiles are XOR-swizzled (T2, both-sides): LDS[row][chunk c] = G[row][c ^ (row&7)]
// where chunk = 16B (8 bf16). Write side swizzles the GLOBAL source chunk
// (global_load_lds dest must stay linear, rule #21); read side XORs the byte col.
// PH1: C = gelu(A@B + bias) -> A1[tok][FFZ] bf16
// !PH1: out[tok][col] = h[tok][col] + 0.5*tprob[tok]*(A@B + bias)
template<int KT, int NT, bool PH1>
__global__ __launch_bounds__(256) void k_gemm(
    const unsigned short* __restrict__ Abase,
    const unsigned short* __restrict__ Bbase,
    const int* __restrict__ list, const int* __restrict__ cnt_g,
    const float* __restrict__ bias,
    unsigned short* __restrict__ A1out,
    const float* __restrict__ hres,
    const float* __restrict__ tprob,
    float* __restrict__ outp)
{
    int e = blockIdx.z;
    int cnt = cnt_g[e];
    int m0 = blockIdx.y * 128;
    if (m0 >= cnt) return;
    int n0 = blockIdx.x * 128;
    int tid = threadIdx.x, w = tid >> 6, l = tid & 63;
    int wr = w >> 1, wc = w & 1;
    __shared__ __align__(16) unsigned short As[128*64];
    __shared__ __align__(16) unsigned short Bs[128*64];

    // staged row for lane l (row&7 == l>>3 for all i,w): source chunk pre-swizzled
    int csw = ((l & 7) ^ (l >> 3)) * 8;   // element offset of swizzled 16B chunk
    const unsigned short* aptr[4];
    const unsigned short* bptr[4];
    #pragma unroll
    for (int i = 0; i < 4; ++i){
        int row = 8*w + (l>>3) + 32*i;
        int g = m0 + row; if (g > cnt-1) g = cnt-1;
        int tok = list[e * NTOK + g];
        aptr[i] = Abase + (size_t)tok * KT + csw;
        bptr[i] = Bbase + ((size_t)e * NT + (n0 + row)) * KT + csw;
    }
    f32x4 acc[4][4] = {};
    for (int k0 = 0; k0 < KT; k0 += 64){
        #pragma unroll
        for (int i = 0; i < 4; ++i)
            gld_lds16(aptr[i] + k0, (char*)As + w*1024 + i*4096);
        #pragma unroll
        for (int i = 0; i < 4; ++i)
            gld_lds16(bptr[i] + k0, (char*)Bs + w*1024 + i*4096);
        __syncthreads();
        // fragment rows: row&7 == l&7 -> read byte-col XOR (l&7)<<4
        int rsw = (l & 7) << 4;
        #pragma unroll
        for (int kk = 0; kk < 2; ++kk){
            bf16x8 a[4], b[4];
            #pragma unroll
            for (int m = 0; m < 4; ++m)
                a[m] = *(const bf16x8*)((const char*)As + (wr*64 + m*16 + (l&15))*128 + ((kk*64 + (l>>4)*16) ^ rsw));
            #pragma unroll
            for (int n = 0; n < 4; ++n)
                b[n] = *(const bf16x8*)((const char*)Bs + (wc*64 + n*16 + (l&15))*128 + ((kk*64 + (l>>4)*16) ^ rsw));
            #pragma unroll
            for (int m = 0; m < 4; ++m)
                #pragma unroll
                for (int n = 0; n < 4; ++n)
                    acc[m][n] = __builtin_amdgcn_mfma_f32_16x16x32_bf16(a[m], b[n], acc[m][n], 0, 0, 0);
        }
        __syncthreads();
    }
    // epilogue: C/D layout col = lane&15, row = (lane>>4)*4 + reg
    #pragma unroll
    for (int m = 0; m < 4; ++m){
        #pragma unroll
        for (int r = 0; r < 4; ++r){
            int row = wr*64 + m*16 + (l>>4)*4 + r;
            int g = m0 + row;
            if (g < cnt){
                int tok = list[e*NTOK + g];
                if (PH1){
                    #pragma unroll
                    for (int n = 0; n < 4; ++n){
                        int col = n0 + wc*64 + n*16 + (l&15);
                        float v = acc[m][n][r] + bias[e*NT + col];
                        A1out[(size_t)tok * FFZ + col] = f2bf(gelu_f(v));
                    }
                } else {
                    float sc = 0.5f * tprob[tok];
                    #pragma unroll
                    for (int n = 0; n < 4; ++n){
                        int col = n0 + wc*64 + n*16 + (l&15);
                        float v = acc[m][n][r] + bias[e*NT + col];
                        size_t o = (size_t)tok * HDIM + col;
                        outp[o] = hres[o] + sc * v;
                    }
                }
            }
        }
    }
}

// ---------------- final: lb_loss ----------------
__global__ void k_final(const float* __restrict__ imp_part, const int* __restrict__ cnt,
                        float* __restrict__ outp){
    __shared__ float imp_s[4];
    int tid = threadIdx.x;
    if (tid < 4){
        float s = 0.f;
        for (int b = 0; b < 256; ++b) s += imp_part[b*4 + tid];
        imp_s[tid] = s;
    }
    __syncthreads();
    if (tid == 0){
        float lb = 0.f;
        #pragma unroll
        for (int e = 0; e < 4; ++e) lb += imp_s[e] * (float)cnt[e];
        outp[(size_t)NTOK * HDIM] = (float)NEXP * lb / ((float)NTOK * (float)NTOK + 1e-8f);
    }
}

extern "C" void kernel_launch(void* const* d_in, const int* in_sizes, int n_in,
                              void* d_out, int out_size, void* d_ws, size_t ws_size,
                              hipStream_t stream){
    const float* h       = (const float*)d_in[0];
    const float* tok_emb = (const float*)d_in[1];
    // d_in[2] = is_mask (unused by the reference math)
    const float* ln_g = (const float*)d_in[3];
    const float* ln_b = (const float*)d_in[4];
    const float* Wg   = (const float*)d_in[5];
    const float* bg   = (const float*)d_in[6];
    const float* Wf   = (const float*)d_in[7];
    const float* bfv  = (const float*)d_in[8];
    const float* Wr   = (const float*)d_in[9];
    const float* br   = (const float*)d_in[10];
    const float* W1   = (const float*)d_in[11];
    const float* b1   = (const float*)d_in[12];
    const float* W2   = (const float*)d_in[13];
    const float* b2   = (const float*)d_in[14];
    float* outp = (float*)d_out;
    char* ws = (char*)d_ws;

    // workspace layout (needs ~134.7 MB)
    unsigned short* h_bf = (unsigned short*)(ws);               // 33554432 B
    unsigned short* W1T  = (unsigned short*)(ws + 33554432);    // 16777216 B  [E][FFZ][HDIM]
    unsigned short* W2T  = (unsigned short*)(ws + 50331648);    // 16777216 B  [E][HDIM][FFZ]
    unsigned short* A1   = (unsigned short*)(ws + 67108864);    // 67108864 B  [NTOK][FFZ]
    float* mu_g  = (float*)(ws + 134217728);
    float* rs_g  = (float*)(ws + 134283264);
    float* tprob = (float*)(ws + 134348800);
    int*   list  = (int*)(ws + 134414336);                      // [E][NTOK]
    int*   cnt   = (int*)(ws + 134676480);                      // [E]
    float* imp   = (float*)(ws + 134676736);                    // [256][E]

    hipMemsetAsync(cnt, 0, NEXP * sizeof(int), stream);
    k_stats<<<NTOK/4, 256, 0, stream>>>(h, h_bf, mu_g, rs_g);
    k_transpose_bf<<<dim3(FFZ/32, HDIM/32, NEXP), dim3(32,8), 0, stream>>>(W1, W1T, HDIM, FFZ);
    k_transpose_bf<<<dim3(HDIM/32, FFZ/32, NEXP), dim3(32,8), 0, stream>>>(W2, W2T, FFZ, HDIM);
    k_route<<<NTOK/64, 256, 0, stream>>>(h, tok_emb, ln_g, ln_b, Wg, bg, Wf, bfv, Wr, br,
                                         mu_g, rs_g, tprob, list, cnt, imp);
    k_gemm<HDIM, FFZ, true><<<dim3(FFZ/128, NTOK/128, NEXP), 256, 0, stream>>>(
        h_bf, W1T, list, cnt, b1, A1, nullptr, nullptr, nullptr);
    k_gemm<FFZ, HDIM, false><<<dim3(HDIM/128, NTOK/128, NEXP), 256, 0, stream>>>(
        A1, W2T, list, cnt, b2, nullptr, h, tprob, outp);
    k_final<<<1, 64, 0, stream>>>(imp, cnt, outp);
}